// Round 9
// baseline (5909.766 us; speedup 1.0000x reference)
//
#include <hip/hip_runtime.h>
#include <hip/hip_bf16.h>
#include <math.h>

#define TPB 256
typedef unsigned short u16;
typedef __attribute__((ext_vector_type(8))) short bf16x8;
typedef __attribute__((ext_vector_type(4))) float f32x4;

__device__ __forceinline__ float b2f(u16 u){ return __uint_as_float(((unsigned)u)<<16); }
__device__ __forceinline__ u16 f2b(float f){
  unsigned x = __float_as_uint(f);
  unsigned r = (x + 0x7fffu + ((x>>16)&1u)) >> 16;
  return (u16)r;
}
__device__ __forceinline__ f32x4 mfma16(bf16x8 a, bf16x8 b, f32x4 c){
  return __builtin_amdgcn_mfma_f32_16x16x32_bf16(a, b, c, 0, 0, 0);
}

// ---------------- Conv1 (per 64-sample chunk) -> NHWC bf16 [64][40][72][64]
// 1440 blocks x 128 positions: weights staged once per block.
__global__ __launch_bounds__(TPB) void conv1_kernel(const float* __restrict__ x,
    const float* __restrict__ w, u16* __restrict__ out){
  __shared__ float wsh[27][64];
  int tid = threadIdx.x;
  for (int idx = tid; idx < 1728; idx += TPB){
    int oc = idx / 27, i = idx - oc*27;
    wsh[i][oc] = w[idx];
  }
  __syncthreads();
  int oc = tid & 63;
  for (int it = 0; it < 32; it++){
    int pos = blockIdx.x*128 + it*4 + (tid>>6);
    int b = pos / 2880; int p = pos - b*2880;
    int oy = p / 72, ox = p - (p/72)*72;
    const float* xb = x + (size_t)b*3*2880;
    float acc = 0.f;
    #pragma unroll
    for (int dy=0; dy<3; dy++){
      int iy = oy-1+dy; if ((unsigned)iy >= 40u) continue;
      #pragma unroll
      for (int dx=0; dx<3; dx++){
        int ix = ox-1+dx; if ((unsigned)ix >= 72u) continue;
        #pragma unroll
        for (int ic=0; ic<3; ic++)
          acc += xb[ic*2880 + iy*72+ix] * wsh[(ic*3+dy)*3+dx][oc];
      }
    }
    out[(size_t)pos*64 + oc] = f2b(fmaxf(acc, 0.f));
  }
}

// ---------------- MaxPool1 3x3 s2 p1 on bf16 NHWC (integer max valid: inputs >= 0)
__global__ __launch_bounds__(TPB) void maxpool1_kernel(const u16* __restrict__ in,
    u16* __restrict__ out){
  int gid = blockIdx.x*TPB + threadIdx.x;     // 737,280 = 64*720*16
  int c4 = gid & 15; int p = (gid>>4) % 720; int b = gid / 11520;
  int oy = p/36, ox = p - (p/36)*36;
  ushort4 m = make_ushort4(0,0,0,0);
  #pragma unroll
  for (int dy=0; dy<3; dy++){
    int iy = oy*2-1+dy; if ((unsigned)iy >= 40u) continue;
    #pragma unroll
    for (int dx=0; dx<3; dx++){
      int ix = ox*2-1+dx; if ((unsigned)ix >= 72u) continue;
      ushort4 v = *(const ushort4*)(in + ((size_t)b*2880 + iy*72+ix)*64 + c4*4);
      m.x = v.x > m.x ? v.x : m.x;  m.y = v.y > m.y ? v.y : m.y;
      m.z = v.z > m.z ? v.z : m.z;  m.w = v.w > m.w ? v.w : m.w;
    }
  }
  *(ushort4*)(out + ((size_t)b*720 + p)*64 + c4*4) = m;
}

// ---------------- Conv2 via MFMA: per sample GEMM M=720, N=64, K=576
__global__ __launch_bounds__(TPB) void conv2_mfma(const u16* __restrict__ p1,
    const u16* __restrict__ wc2, float* __restrict__ c2){
  int s = blockIdx.y;
  int wave = threadIdx.x>>6, lane = threadIdx.x&63, q = lane>>4, li = lane&15;
  int mt = blockIdx.x*4 + wave;
  if (mt >= 45) return;
  int m0 = mt*16;
  int pos = m0 + li;
  int oy = pos/36, ox = pos - (pos/36)*36;
  const u16* ps = p1 + (size_t)s*720*64;
  f32x4 acc[4];
  #pragma unroll
  for (int nt=0;nt<4;nt++) acc[nt] = (f32x4){0.f,0.f,0.f,0.f};
  #pragma unroll
  for (int ks=0; ks<18; ks++){
    const int r9 = ks>>1;
    const int dy = r9/3, dx = r9 - 3*(r9/3);
    int k0 = ks*32 + q*8;
    int ic8 = (ks&1)*32 + q*8;
    int iy = oy-1+dy, ix = ox-1+dx;
    bf16x8 a;
    if ((unsigned)iy < 20u && (unsigned)ix < 36u)
      a = *(const bf16x8*)(ps + (size_t)(iy*36+ix)*64 + ic8);
    else
      a = (bf16x8){0,0,0,0,0,0,0,0};
    #pragma unroll
    for (int nt=0;nt<4;nt++){
      bf16x8 b = *(const bf16x8*)(wc2 + (size_t)(nt*16+li)*576 + k0);
      acc[nt] = mfma16(a, b, acc[nt]);
    }
  }
  #pragma unroll
  for (int nt=0;nt<4;nt++){
    int oc = nt*16 + li;
    #pragma unroll
    for (int r=0;r<4;r++){
      int prow = m0 + q*4 + r;
      c2[((size_t)s*720 + prow)*64 + oc] = fmaxf(acc[nt][r], 0.f);
    }
  }
}

// ---------------- MaxPool2 + pos_emb fused
__global__ __launch_bounds__(TPB) void pool2pos_kernel(const float* __restrict__ c2,
    const float* __restrict__ pos, float* __restrict__ t){
  int gid = blockIdx.x*TPB + threadIdx.x;     // 737,280
  int d4 = gid & 15; int n = (gid>>4) % 180; int b = gid / 2880;
  int oy = n/18, ox = n - (n/18)*18;
  float4 m = make_float4(0.f,0.f,0.f,0.f);
  #pragma unroll
  for (int dy=0; dy<3; dy++){
    int iy = oy*2-1+dy; if ((unsigned)iy >= 20u) continue;
    #pragma unroll
    for (int dx=0; dx<3; dx++){
      int ix = ox*2-1+dx; if ((unsigned)ix >= 36u) continue;
      float4 v = *(const float4*)(c2 + ((size_t)b*720 + iy*36+ix)*64 + d4*4);
      m.x = fmaxf(m.x, v.x); m.y = fmaxf(m.y, v.y);
      m.z = fmaxf(m.z, v.z); m.w = fmaxf(m.w, v.w);
    }
  }
  float4 pe = *(const float4*)(pos + n*64 + d4*4);
  *(float4*)(t + ((size_t)b*180 + n)*64 + d4*4) =
      make_float4(m.x+pe.x, m.y+pe.y, m.z+pe.z, m.w+pe.w);
}

// ---------------- weight transpose+cvt: src[l][R][C] f32 -> dst[l][C][R] bf16
__global__ __launch_bounds__(TPB) void tcvt_kernel(const float* __restrict__ src,
    u16* __restrict__ dst, int R, int C, int total){
  int gid = blockIdx.x*TPB + threadIdx.x;
  if (gid >= total) return;
  int rc = R*C;
  int l = gid / rc; int rem = gid - l*rc; int c = rem / R; int r = rem - c*R;
  dst[gid] = f2b(src[(size_t)l*rc + (size_t)r*C + c]);
}

__global__ __launch_bounds__(TPB) void tcvt_conv(const float* __restrict__ src,
    u16* __restrict__ dst, int total){
  int gid = blockIdx.x*TPB + threadIdx.x;
  if (gid >= total) return;
  int oc = gid / 576, k = gid - oc*576;
  int r9 = k >> 6, ic = k & 63;
  dst[gid] = f2b(src[oc*576 + ic*9 + r9]);
}

__global__ __launch_bounds__(TPB) void tcvt_cw(const float* __restrict__ src,
    float* __restrict__ dst){
  int gid = blockIdx.x*TPB + threadIdx.x;
  if (gid >= 393216) return;
  int i = gid / 384, rem = gid - i*384;
  int o = rem >> 3, e = rem & 7;
  dst[gid] = src[i*384 + e*48 + o];
}

// ---------------- LayerNorm (dim 64) -> bf16 H (once, before the loop)
__global__ __launch_bounds__(TPB) void ln_kernel(const float* __restrict__ x,
    const float* __restrict__ g, const float* __restrict__ bta, u16* __restrict__ out){
  int row = blockIdx.x*4 + (threadIdx.x>>6);
  int lane = threadIdx.x & 63;
  float v = x[(size_t)row*64 + lane];
  float s = v;
  #pragma unroll
  for (int off=32; off; off>>=1) s += __shfl_xor(s, off);
  float mean = s * (1.f/64.f);
  float d = v - mean;
  float q = d*d;
  #pragma unroll
  for (int off=32; off; off>>=1) q += __shfl_xor(q, off);
  float r = rsqrtf(q*(1.f/64.f) + 1e-5f);
  out[(size_t)row*64 + lane] = f2b(d*r*g[lane] + bta[lane]);
}

// ---------------- fused QKV-proj + attention (S^T form): one block per (head, sample)
// LDS strides all 16-B multiples; P-transpose via shuffles (no LDS round-trip).
__global__ __launch_bounds__(TPB) void attn_fused(const u16* __restrict__ Hg,
    const u16* __restrict__ W, u16* __restrict__ Og){
  __shared__ __align__(16) u16 Kl[192][72];   // K [key][d]
  __shared__ __align__(16) u16 VT[64][200];   // V^T [d][key]
  __shared__ __align__(16) u16 Pw[4][16][72]; // wave-private: Q transpose, then O transpose
  int h = blockIdx.x, s = blockIdx.y;
  int tid = threadIdx.x, wave = tid>>6, lane = tid&63;
  int q = lane>>4, li = lane&15;
  const u16* Hb = Hg + (size_t)s*180*64;
  const u16* Wq = W + (size_t)(h*64)*64;
  const u16* Wk = W + (size_t)(768 + h*64)*64;
  const u16* Wv = W + (size_t)(1536 + h*64)*64;
  // phase 1: K and V^T into LDS (rows/cols >=180 are clamped clones, masked later)
  for (int p = wave; p < 12; p += 4){
    int m0 = p*16;
    int ar = m0 + li; if (ar > 179) ar = 179;
    const u16* hrow = Hb + (size_t)ar*64 + q*8;
    bf16x8 a0 = *(const bf16x8*)hrow;
    bf16x8 a1 = *(const bf16x8*)(hrow+32);
    #pragma unroll
    for (int nt=0; nt<4; nt++){
      const u16* kr = Wk + (size_t)(nt*16+li)*64 + q*8;
      bf16x8 b0 = *(const bf16x8*)kr;
      bf16x8 b1 = *(const bf16x8*)(kr+32);
      f32x4 ck = {0.f,0.f,0.f,0.f};
      ck = mfma16(a0,b0,ck); ck = mfma16(a1,b1,ck);
      #pragma unroll
      for (int r=0;r<4;r++) Kl[m0+q*4+r][nt*16+li] = f2b(ck[r]);
      const u16* vr = Wv + (size_t)(nt*16+li)*64 + q*8;
      bf16x8 d0 = *(const bf16x8*)vr;
      bf16x8 d1 = *(const bf16x8*)(vr+32);
      f32x4 cv = {0.f,0.f,0.f,0.f};
      cv = mfma16(a0,d0,cv); cv = mfma16(a1,d1,cv);
      #pragma unroll
      for (int r=0;r<4;r++) VT[nt*16+li][m0+q*4+r] = f2b(cv[r]);
    }
  }
  __syncthreads();
  // phase 2: per Q-tile: Q -> S^T -> exp -> PV (O^T) -> scale -> store
  for (int p = wave; p < 12; p += 4){
    int m0 = p*16;
    int ar = m0 + li; if (ar > 179) ar = 179;
    const u16* hrow = Hb + (size_t)ar*64 + q*8;
    bf16x8 a0 = *(const bf16x8*)hrow;
    bf16x8 a1 = *(const bf16x8*)(hrow+32);
    #pragma unroll
    for (int nt=0; nt<4; nt++){
      const u16* qr = Wq + (size_t)(nt*16+li)*64 + q*8;
      bf16x8 b0 = *(const bf16x8*)qr;
      bf16x8 b1 = *(const bf16x8*)(qr+32);
      f32x4 c = {0.f,0.f,0.f,0.f};
      c = mfma16(a0,b0,c); c = mfma16(a1,b1,c);
      #pragma unroll
      for (int r=0;r<4;r++) Pw[wave][q*4+r][nt*16+li] = f2b(c[r]*0.125f);
    }
    bf16x8 qf0 = *(const bf16x8*)&Pw[wave][li][q*8];
    bf16x8 qf1 = *(const bf16x8*)&Pw[wave][li][32+q*8];
    // S^T tiles: lane (q,li) holds keys {16t+q*4+r} for q-row li. exp, sum, pack.
    int p01[12], p23[12];
    float psum = 0.f;
    #pragma unroll
    for (int t=0;t<12;t++){
      bf16x8 k0 = *(const bf16x8*)&Kl[t*16+li][q*8];
      bf16x8 k1 = *(const bf16x8*)&Kl[t*16+li][32+q*8];
      f32x4 c = {0.f,0.f,0.f,0.f};
      c = mfma16(k0, qf0, c);
      c = mfma16(k1, qf1, c);
      float e0,e1,e2,e3;
      if (t==11 && q>=1){ e0=0.f; e1=0.f; e2=0.f; e3=0.f; }
      else { e0=__expf(c[0]); e1=__expf(c[1]); e2=__expf(c[2]); e3=__expf(c[3]); }
      psum += (e0+e1)+(e2+e3);
      p01[t] = (int)((((unsigned)f2b(e1))<<16) | f2b(e0));
      p23[t] = (int)((((unsigned)f2b(e3))<<16) | f2b(e2));
    }
    psum += __shfl_xor(psum, 16);
    psum += __shfl_xor(psum, 32);
    float inv = 1.f/psum;                      // full sum for q-row li (all lanes)
    // PV: O^T[d][qrow]; B-frag built by cross-lane pulls of packed exp values
    f32x4 acc[4];
    #pragma unroll
    for (int nd=0;nd<4;nd++) acc[nd] = (f32x4){0.f,0.f,0.f,0.f};
    int qc0 = (q&1)*2;
    int l0 = qc0*16 + li, l1 = l0 + 16;
    int th = q>>1;
    #pragma unroll
    for (int kb=0; kb<6; kb++){
      int sa0 = __shfl(p01[2*kb],   l0), sb0 = __shfl(p01[2*kb+1], l0);
      int sa1 = __shfl(p23[2*kb],   l0), sb1 = __shfl(p23[2*kb+1], l0);
      int sa2 = __shfl(p01[2*kb],   l1), sb2 = __shfl(p01[2*kb+1], l1);
      int sa3 = __shfl(p23[2*kb],   l1), sb3 = __shfl(p23[2*kb+1], l1);
      union { bf16x8 v; int u[4]; } bf;
      bf.u[0] = th ? sb0 : sa0;
      bf.u[1] = th ? sb1 : sa1;
      bf.u[2] = th ? sb2 : sa2;
      bf.u[3] = th ? sb3 : sa3;
      #pragma unroll
      for (int nd=0; nd<4; nd++){
        bf16x8 vf = *(const bf16x8*)&VT[nd*16+li][kb*32 + q*8];
        acc[nd] = mfma16(vf, bf.v, acc[nd]);
      }
    }
    // epilogue: scale by 1/sum, transpose through Pw, coalesced store
    #pragma unroll
    for (int nd=0; nd<4; nd++){
      #pragma unroll
      for (int r=0;r<4;r++)
        Pw[wave][li][nd*16+q*4+r] = f2b(acc[nd][r]*inv);
    }
    int g8 = lane>>3, u8 = lane&7;
    #pragma unroll
    for (int it=0; it<2; it++){
      int rr = it*8 + g8;
      int row = m0 + rr;
      bf16x8 ov = *(const bf16x8*)&Pw[wave][rr][u8*8];
      if (row < 180)
        *(bf16x8*)(Og + (size_t)(s*180+row)*768 + h*64 + u8*8) = ov;
    }
  }
}

// ---------------- out-proj + residual + fused LN2 -> Hg
__global__ __launch_bounds__(TPB) void gemm_outp(const u16* __restrict__ Og,
    const u16* __restrict__ WOT, const float* __restrict__ outb,
    const float* __restrict__ lng, const float* __restrict__ lnb,
    float* __restrict__ t, u16* __restrict__ HgOut){
  int wave = threadIdx.x>>6, lane = threadIdx.x&63, q = lane>>4, li = lane&15;
  int m0 = blockIdx.x*64 + wave*16;
  f32x4 acc[4];
  #pragma unroll
  for (int nd=0;nd<4;nd++) acc[nd] = (f32x4){0.f,0.f,0.f,0.f};
  for (int kb=0; kb<24; kb++){
    bf16x8 a = *(const bf16x8*)(Og + (size_t)(m0+li)*768 + kb*32 + q*8);
    #pragma unroll
    for (int nd=0;nd<4;nd++){
      bf16x8 b = *(const bf16x8*)(WOT + (size_t)(nd*16+li)*768 + kb*32 + q*8);
      acc[nd] = mfma16(a, b, acc[nd]);
    }
  }
  float tv[4][4]; float gv[4], bvn[4];
  #pragma unroll
  for (int nd=0;nd<4;nd++){
    int col = nd*16 + li;
    float bv = outb[col];
    gv[nd] = lng[col]; bvn[nd] = lnb[col];
    #pragma unroll
    for (int r=0;r<4;r++){
      size_t off = (size_t)(m0 + q*4 + r)*64 + col;
      float v = t[off] + acc[nd][r] + bv;
      t[off] = v;
      tv[nd][r] = v;
    }
  }
  #pragma unroll
  for (int r=0;r<4;r++){
    float s = tv[0][r]+tv[1][r]+tv[2][r]+tv[3][r];
    #pragma unroll
    for (int off=8; off; off>>=1) s += __shfl_xor(s, off);
    float mean = s*(1.f/64.f);
    float qs = 0.f;
    #pragma unroll
    for (int nd=0;nd<4;nd++){ float d = tv[nd][r]-mean; qs += d*d; }
    #pragma unroll
    for (int off=8; off; off>>=1) qs += __shfl_xor(qs, off);
    float rinv = rsqrtf(qs*(1.f/64.f) + 1e-5f);
    size_t rowoff = (size_t)(m0 + q*4 + r)*64;
    #pragma unroll
    for (int nd=0;nd<4;nd++){
      int col = nd*16 + li;
      HgOut[rowoff + col] = f2b((tv[nd][r]-mean)*rinv*gv[nd] + bvn[nd]);
    }
  }
}

// ---------------- fused ffn: gelu(Hg@W1^T+b1) -> LDS panel -> t+=@W2^T+b2 -> LN(next) -> Hg
__global__ __launch_bounds__(TPB) void gemm_ffn(const u16* __restrict__ Hg,
    const u16* __restrict__ W1, const float* __restrict__ b1,
    const u16* __restrict__ W2, const float* __restrict__ b2,
    const float* __restrict__ lng, const float* __restrict__ lnb,
    float* __restrict__ t, u16* __restrict__ HgOut){
  __shared__ __align__(16) u16 panel[4][16][264];
  int wave = threadIdx.x>>6, lane = threadIdx.x&63, q = lane>>4, li = lane&15;
  int m0 = blockIdx.x*64 + wave*16;
  const u16* arow = Hg + (size_t)(m0+li)*64 + q*8;
  bf16x8 a0 = *(const bf16x8*)arow;
  bf16x8 a1 = *(const bf16x8*)(arow + 32);
  for (int nt=0; nt<16; nt++){
    const u16* brow = W1 + (size_t)(nt*16+li)*64 + q*8;
    bf16x8 b0 = *(const bf16x8*)brow;
    bf16x8 b1v = *(const bf16x8*)(brow + 32);
    f32x4 c = {0.f,0.f,0.f,0.f};
    c = mfma16(a0, b0, c);
    c = mfma16(a1, b1v, c);
    int col = nt*16 + li;
    float bv = b1[col];
    #pragma unroll
    for (int r=0;r<4;r++){
      float v = c[r] + bv;
      v = v*0.5f*(1.f + erff(v*0.70710678118f));
      panel[wave][q*4+r][col] = f2b(v);
    }
  }
  bf16x8 ap[8];
  #pragma unroll
  for (int kb=0;kb<8;kb++) ap[kb] = *(const bf16x8*)&panel[wave][li][kb*32 + q*8];
  f32x4 acc[4];
  #pragma unroll
  for (int nd=0;nd<4;nd++) acc[nd] = (f32x4){0.f,0.f,0.f,0.f};
  #pragma unroll
  for (int kb=0; kb<8; kb++){
    #pragma unroll
    for (int nd=0;nd<4;nd++){
      bf16x8 b = *(const bf16x8*)(W2 + (size_t)(nd*16+li)*256 + kb*32 + q*8);
      acc[nd] = mfma16(ap[kb], b, acc[nd]);
    }
  }
  float tv[4][4]; float gv[4], bvn[4];
  #pragma unroll
  for (int nd=0;nd<4;nd++){
    int col = nd*16 + li;
    float bv = b2[col];
    gv[nd] = lng[col]; bvn[nd] = lnb[col];
    #pragma unroll
    for (int r=0;r<4;r++){
      size_t off = (size_t)(m0 + q*4 + r)*64 + col;
      float v = t[off] + acc[nd][r] + bv;
      t[off] = v;
      tv[nd][r] = v;
    }
  }
  #pragma unroll
  for (int r=0;r<4;r++){
    float s = tv[0][r]+tv[1][r]+tv[2][r]+tv[3][r];
    #pragma unroll
    for (int off=8; off; off>>=1) s += __shfl_xor(s, off);
    float mean = s*(1.f/64.f);
    float qs = 0.f;
    #pragma unroll
    for (int nd=0;nd<4;nd++){ float d = tv[nd][r]-mean; qs += d*d; }
    #pragma unroll
    for (int off=8; off; off>>=1) qs += __shfl_xor(qs, off);
    float rinv = rsqrtf(qs*(1.f/64.f) + 1e-5f);
    size_t rowoff = (size_t)(m0 + q*4 + r)*64;
    #pragma unroll
    for (int nd=0;nd<4;nd++){
      int col = nd*16 + li;
      HgOut[rowoff + col] = f2b((tv[nd][r]-mean)*rinv*gv[nd] + bvn[nd]);
    }
  }
}

// ---------------- PrimaryCaps via MFMA + fused squash: one block per sample
__global__ __launch_bounds__(TPB) void pcaps_mfma(const float* __restrict__ t,
    const u16* __restrict__ wpc, const float* __restrict__ bias, float* __restrict__ caps){
  int b = blockIdx.x;
  int wave = threadIdx.x>>6, lane = threadIdx.x&63, q = lane>>4, li = lane&15;
  int mt = wave & 1, nh = wave >> 1;
  const float* tb = t + (size_t)b*180*64;
  int pos_a = mt*16 + li;
  int oy_a = pos_a >> 3, ox_a = pos_a & 7;
  f32x4 acc[8];
  #pragma unroll
  for (int nt=0;nt<8;nt++) acc[nt] = (f32x4){0.f,0.f,0.f,0.f};
  for (int ks=0; ks<18; ks++){
    int k0 = ks*32 + q*8;
    int r9 = k0 >> 6, ic = k0 & 63;
    int dy = r9/3, dx = r9 - 3*dy;
    const float* src = tb + ((2*oy_a+dy)*18 + (2*ox_a+dx))*64 + ic;
    float4 f0 = *(const float4*)src;
    float4 f1 = *(const float4*)(src+4);
    bf16x8 a;
    a[0]=(short)f2b(f0.x); a[1]=(short)f2b(f0.y); a[2]=(short)f2b(f0.z); a[3]=(short)f2b(f0.w);
    a[4]=(short)f2b(f1.x); a[5]=(short)f2b(f1.y); a[6]=(short)f2b(f1.z); a[7]=(short)f2b(f1.w);
    #pragma unroll
    for (int nt=0;nt<8;nt++){
      bf16x8 bb8 = *(const bf16x8*)(wpc + (size_t)(nh*128 + nt*16 + li)*576 + k0);
      acc[nt] = mfma16(a, bb8, acc[nt]);
    }
  }
  #pragma unroll
  for (int nt=0;nt<8;nt++){
    int oc = nh*128 + nt*16 + li;
    float bv = bias[oc];
    #pragma unroll
    for (int r=0;r<4;r++){
      int prow = mt*16 + q*4 + r;
      float val = acc[nt][r] + bv;
      float l2 = val*val;
      l2 += __shfl_xor(l2, 1);
      l2 += __shfl_xor(l2, 2);
      l2 += __shfl_xor(l2, 4);
      float sc = (l2 > 0.f) ? l2/((1.f+l2)*sqrtf(l2)) : 0.f;
      caps[((size_t)b*1024 + (oc>>3)*32 + prow)*8 + (oc&7)] = val*sc;
    }
  }
}

// ---------------- u[b,i,o] = caps[b,i,:] . cwT[i,o,:]
__global__ __launch_bounds__(TPB) void u_kernel(const float* __restrict__ caps,
    const float* __restrict__ cwT, float* __restrict__ u){
  int gid = blockIdx.x*TPB + threadIdx.x;
  int o = gid % 48; int i = (gid/48) & 1023; int b = gid/(48*1024);
  const float* cp = caps + ((size_t)b*1024 + i)*8;
  const float* wp = cwT + ((size_t)i*48 + o)*8;
  float4 c0 = *(const float4*)cp, c1 = *(const float4*)(cp+4);
  float4 w0 = *(const float4*)wp, w1 = *(const float4*)(wp+4);
  u[gid] = c0.x*w0.x + c0.y*w0.y + c0.z*w0.z + c0.w*w0.w
         + c1.x*w1.x + c1.y*w1.y + c1.z*w1.z + c1.w*w1.w;
}

__global__ __launch_bounds__(TPB) void routing_kernel(const float* __restrict__ u,
    const float* __restrict__ b_route, float* __restrict__ out){
  __shared__ float bb[3072];
  __shared__ float vsh[48];
  __shared__ float red[4][48];
  __shared__ float ssh[48];
  int b = blockIdx.x, tid = threadIdx.x;
  const float* ub = u + (size_t)b*49152;
  for (int idx=tid; idx<3072; idx+=TPB) bb[idx] = b_route[idx];
  __syncthreads();
  for (int it=0; it<4; it++){
    if (it > 0){
      for (int idx=tid; idx<3072; idx+=TPB){
        int i = idx/3, j = idx - i*3;
        const float* up = ub + i*48 + j*16;
        float s = 0.f;
        #pragma unroll
        for (int e=0;e<16;e++) s += up[e]*vsh[j*16+e];
        bb[idx] += s;
      }
      __syncthreads();
    }
    float acc[48];
    #pragma unroll
    for (int q2=0;q2<48;q2++) acc[q2] = 0.f;
    for (int i=tid; i<1024; i+=TPB){
      float b0=bb[i*3], b1=bb[i*3+1], b2v=bb[i*3+2];
      float m = fmaxf(b0, fmaxf(b1, b2v));
      float e0=__expf(b0-m), e1=__expf(b1-m), e2=__expf(b2v-m);
      float inv = 1.f/(e0+e1+e2);
      float c0=e0*inv, c1=e1*inv, c2=e2*inv;
      const float* up = ub + i*48;
      #pragma unroll
      for (int e=0;e<16;e++){
        acc[e]    += c0*up[e];
        acc[16+e] += c1*up[16+e];
        acc[32+e] += c2*up[32+e];
      }
    }
    #pragma unroll
    for (int q2=0;q2<48;q2++){
      float v = acc[q2];
      #pragma unroll
      for (int off=32; off; off>>=1) v += __shfl_xor(v, off);
      if ((tid&63)==0) red[tid>>6][q2] = v;
    }
    __syncthreads();
    if (tid < 48) ssh[tid] = red[0][tid]+red[1][tid]+red[2][tid]+red[3][tid];
    __syncthreads();
    if (tid < 48){
      int j = tid >> 4;
      float l2 = 0.f;
      #pragma unroll
      for (int e=0;e<16;e++) l2 += ssh[j*16+e]*ssh[j*16+e];
      float sc = (l2 > 0.f) ? l2/((1.f+l2)*sqrtf(l2)) : 0.f;
      vsh[tid] = ssh[tid]*sc;
    }
    __syncthreads();
  }
  if (tid < 3){
    float l2 = 0.f;
    #pragma unroll
    for (int e=0;e<16;e++) l2 += vsh[tid*16+e]*vsh[tid*16+e];
    out[b*3+tid] = sqrtf(l2);
  }
}

extern "C" void kernel_launch(void* const* d_in, const int* in_sizes, int n_in,
                              void* d_out, int out_size, void* d_ws, size_t ws_size,
                              hipStream_t stream){
  const float* x       = (const float*)d_in[0];
  const float* conv1_w = (const float*)d_in[1];
  const float* conv2_w = (const float*)d_in[2];
  const float* pos_emb = (const float*)d_in[3];
  const float* ln1_g   = (const float*)d_in[4];
  const float* ln1_b   = (const float*)d_in[5];
  const float* qkv_w   = (const float*)d_in[6];
  const float* out_w   = (const float*)d_in[7];
  const float* out_b   = (const float*)d_in[8];
  const float* ln2_g   = (const float*)d_in[9];
  const float* ln2_b   = (const float*)d_in[10];
  const float* ff1_w   = (const float*)d_in[11];
  const float* ff1_b   = (const float*)d_in[12];
  const float* ff2_w   = (const float*)d_in[13];
  const float* ff2_b   = (const float*)d_in[14];
  const float* pc_w    = (const float*)d_in[15];
  const float* pc_b    = (const float*)d_in[16];
  const float* caps_w  = (const float*)d_in[17];
  const float* b_route = (const float*)d_in[18];
  float* out = (float*)d_out;

  // ---- workspace: peak 95,920,128 B (< 97.3 MB proven safe) ----
  char* ws = (char*)d_ws;
  float* t_buf = (float*)(ws);                  // [46080,64] f32
  u16*  Hg    = (u16*)(ws + 11796480);          // [46080,64] bf16
  u16*  WQKVT = (u16*)(ws + 17694720);          // [12][2304][64]
  u16*  WOT   = (u16*)(ws + 21233664);          // [12][64][768]
  u16*  WF1T  = (u16*)(ws + 22413312);          // [12][256][64]
  u16*  WF2T  = (u16*)(ws + 22806528);          // [12][64][256]
  u16*  wpc   = (u16*)(ws + 23199744);          // [256][576] bf16
  float* cwT  = (float*)(ws + 23494656);        // [1024][48][8]
  u16*  wc2   = (u16*)(ws + 25067520);          // [64][576] bf16
  char* win   = ws + 25141248;                  // 70,778,880 B window
  u16*  Og    = (u16*)win;                      // [46080][768] bf16
  u16*  p1out = (u16*)win;                      // [256][720][64] bf16
  u16*  c1out = (u16*)(win + 23592960);         // [64][2880][64] bf16 chunk
  float* c2out = (float*)(win + 23592960);      // [256][720][64] f32
  float* caps  = (float*)(win);                 // tail
  float* u_buf = (float*)(win + 8388608);       // tail

  // ---- weight prep ----
  tcvt_kernel<<<6912, TPB, 0, stream>>>(qkv_w, WQKVT, 64, 2304, 12*64*2304);
  tcvt_kernel<<<2304, TPB, 0, stream>>>(out_w, WOT, 768, 64, 12*768*64);
  tcvt_kernel<<<768, TPB, 0, stream>>>(ff1_w, WF1T, 64, 256, 12*64*256);
  tcvt_kernel<<<768, TPB, 0, stream>>>(ff2_w, WF2T, 256, 64, 12*256*64);
  tcvt_conv<<<576, TPB, 0, stream>>>(pc_w, wpc, 147456);
  tcvt_conv<<<144, TPB, 0, stream>>>(conv2_w, wc2, 36864);
  tcvt_cw<<<1536, TPB, 0, stream>>>(caps_w, cwT);

  // ---- conv-embed ----
  for (int c = 0; c < 4; c++){
    conv1_kernel<<<1440, TPB, 0, stream>>>(x + (size_t)c*64*3*2880, conv1_w, c1out);
    maxpool1_kernel<<<2880, TPB, 0, stream>>>(c1out, p1out + (size_t)c*64*720*64);
  }
  conv2_mfma<<<dim3(12,256), TPB, 0, stream>>>(p1out, wc2, c2out);
  pool2pos_kernel<<<2880, TPB, 0, stream>>>(c2out, pos_emb, t_buf);

  // ---- transformer ----
  ln_kernel<<<11520, TPB, 0, stream>>>(t_buf, ln1_g, ln1_b, Hg);
  for (int itr=0; itr<24; itr++){
    int l = itr % 12;
    int ln = (itr+1) % 12;
    attn_fused<<<dim3(12,256), TPB, 0, stream>>>(Hg, WQKVT + (size_t)l*2304*64, Og);
    gemm_outp<<<720, TPB, 0, stream>>>(Og, WOT + (size_t)l*64*768, out_b + l*64,
                                       ln2_g + l*64, ln2_b + l*64, t_buf, Hg);
    gemm_ffn<<<720, TPB, 0, stream>>>(Hg, WF1T + (size_t)l*256*64, ff1_b + l*256,
                                      WF2T + (size_t)l*64*256, ff2_b + l*64,
                                      ln1_g + ln*64, ln1_b + ln*64, t_buf, Hg);
  }

  // ---- capsule head ----
  pcaps_mfma<<<256, TPB, 0, stream>>>(t_buf, wpc, pc_b, caps);
  u_kernel<<<49152, TPB, 0, stream>>>(caps, cwT, u_buf);
  routing_kernel<<<256, TPB, 0, stream>>>(u_buf, b_route, out);
}

// Round 10
// 4935.909 us; speedup vs baseline: 1.1973x; 1.1973x over previous
//
#include <hip/hip_runtime.h>
#include <hip/hip_bf16.h>
#include <math.h>

#define TPB 256
typedef unsigned short u16;
typedef __attribute__((ext_vector_type(8))) short bf16x8;
typedef __attribute__((ext_vector_type(4))) float f32x4;

__device__ __forceinline__ float b2f(u16 u){ return __uint_as_float(((unsigned)u)<<16); }
__device__ __forceinline__ u16 f2b(float f){
  unsigned x = __float_as_uint(f);
  unsigned r = (x + 0x7fffu + ((x>>16)&1u)) >> 16;
  return (u16)r;
}
__device__ __forceinline__ f32x4 mfma16(bf16x8 a, bf16x8 b, f32x4 c){
  return __builtin_amdgcn_mfma_f32_16x16x32_bf16(a, b, c, 0, 0, 0);
}

// ---------------- Conv1 (per 64-sample chunk) -> NHWC bf16 [64][40][72][64]
__global__ __launch_bounds__(TPB) void conv1_kernel(const float* __restrict__ x,
    const float* __restrict__ w, u16* __restrict__ out){
  __shared__ float wsh[27][64];
  int tid = threadIdx.x;
  for (int idx = tid; idx < 1728; idx += TPB){
    int oc = idx / 27, i = idx - oc*27;
    wsh[i][oc] = w[idx];
  }
  __syncthreads();
  int oc = tid & 63;
  for (int it = 0; it < 32; it++){
    int pos = blockIdx.x*128 + it*4 + (tid>>6);
    int b = pos / 2880; int p = pos - b*2880;
    int oy = p / 72, ox = p - (p/72)*72;
    const float* xb = x + (size_t)b*3*2880;
    float acc = 0.f;
    #pragma unroll
    for (int dy=0; dy<3; dy++){
      int iy = oy-1+dy; if ((unsigned)iy >= 40u) continue;
      #pragma unroll
      for (int dx=0; dx<3; dx++){
        int ix = ox-1+dx; if ((unsigned)ix >= 72u) continue;
        #pragma unroll
        for (int ic=0; ic<3; ic++)
          acc += xb[ic*2880 + iy*72+ix] * wsh[(ic*3+dy)*3+dx][oc];
      }
    }
    out[(size_t)pos*64 + oc] = f2b(fmaxf(acc, 0.f));
  }
}

// ---------------- MaxPool1 3x3 s2 p1 on bf16 NHWC (integer max valid: inputs >= 0)
__global__ __launch_bounds__(TPB) void maxpool1_kernel(const u16* __restrict__ in,
    u16* __restrict__ out){
  int gid = blockIdx.x*TPB + threadIdx.x;     // 737,280
  int c4 = gid & 15; int p = (gid>>4) % 720; int b = gid / 11520;
  int oy = p/36, ox = p - (p/36)*36;
  ushort4 m = make_ushort4(0,0,0,0);
  #pragma unroll
  for (int dy=0; dy<3; dy++){
    int iy = oy*2-1+dy; if ((unsigned)iy >= 40u) continue;
    #pragma unroll
    for (int dx=0; dx<3; dx++){
      int ix = ox*2-1+dx; if ((unsigned)ix >= 72u) continue;
      ushort4 v = *(const ushort4*)(in + ((size_t)b*2880 + iy*72+ix)*64 + c4*4);
      m.x = v.x > m.x ? v.x : m.x;  m.y = v.y > m.y ? v.y : m.y;
      m.z = v.z > m.z ? v.z : m.z;  m.w = v.w > m.w ? v.w : m.w;
    }
  }
  *(ushort4*)(out + ((size_t)b*720 + p)*64 + c4*4) = m;
}

// ---------------- Conv2 via MFMA: per sample GEMM M=720, N=64, K=576
__global__ __launch_bounds__(TPB) void conv2_mfma(const u16* __restrict__ p1,
    const u16* __restrict__ wc2, float* __restrict__ c2){
  int s = blockIdx.y;
  int wave = threadIdx.x>>6, lane = threadIdx.x&63, q = lane>>4, li = lane&15;
  int mt = blockIdx.x*4 + wave;
  if (mt >= 45) return;
  int m0 = mt*16;
  int pos = m0 + li;
  int oy = pos/36, ox = pos - (pos/36)*36;
  const u16* ps = p1 + (size_t)s*720*64;
  f32x4 acc[4];
  #pragma unroll
  for (int nt=0;nt<4;nt++) acc[nt] = (f32x4){0.f,0.f,0.f,0.f};
  #pragma unroll
  for (int ks=0; ks<18; ks++){
    const int r9 = ks>>1;
    const int dy = r9/3, dx = r9 - 3*(r9/3);
    int k0 = ks*32 + q*8;
    int ic8 = (ks&1)*32 + q*8;
    int iy = oy-1+dy, ix = ox-1+dx;
    bf16x8 a;
    if ((unsigned)iy < 20u && (unsigned)ix < 36u)
      a = *(const bf16x8*)(ps + (size_t)(iy*36+ix)*64 + ic8);
    else
      a = (bf16x8){0,0,0,0,0,0,0,0};
    #pragma unroll
    for (int nt=0;nt<4;nt++){
      bf16x8 b = *(const bf16x8*)(wc2 + (size_t)(nt*16+li)*576 + k0);
      acc[nt] = mfma16(a, b, acc[nt]);
    }
  }
  #pragma unroll
  for (int nt=0;nt<4;nt++){
    int oc = nt*16 + li;
    #pragma unroll
    for (int r=0;r<4;r++){
      int prow = m0 + q*4 + r;
      c2[((size_t)s*720 + prow)*64 + oc] = fmaxf(acc[nt][r], 0.f);
    }
  }
}

// ---------------- MaxPool2 + pos_emb fused
__global__ __launch_bounds__(TPB) void pool2pos_kernel(const float* __restrict__ c2,
    const float* __restrict__ pos, float* __restrict__ t){
  int gid = blockIdx.x*TPB + threadIdx.x;     // 737,280
  int d4 = gid & 15; int n = (gid>>4) % 180; int b = gid / 2880;
  int oy = n/18, ox = n - (n/18)*18;
  float4 m = make_float4(0.f,0.f,0.f,0.f);
  #pragma unroll
  for (int dy=0; dy<3; dy++){
    int iy = oy*2-1+dy; if ((unsigned)iy >= 20u) continue;
    #pragma unroll
    for (int dx=0; dx<3; dx++){
      int ix = ox*2-1+dx; if ((unsigned)ix >= 36u) continue;
      float4 v = *(const float4*)(c2 + ((size_t)b*720 + iy*36+ix)*64 + d4*4);
      m.x = fmaxf(m.x, v.x); m.y = fmaxf(m.y, v.y);
      m.z = fmaxf(m.z, v.z); m.w = fmaxf(m.w, v.w);
    }
  }
  float4 pe = *(const float4*)(pos + n*64 + d4*4);
  *(float4*)(t + ((size_t)b*180 + n)*64 + d4*4) =
      make_float4(m.x+pe.x, m.y+pe.y, m.z+pe.z, m.w+pe.w);
}

// ---------------- weight transpose+cvt: src[l][R][C] f32 -> dst[l][C][R] bf16
__global__ __launch_bounds__(TPB) void tcvt_kernel(const float* __restrict__ src,
    u16* __restrict__ dst, int R, int C, int total){
  int gid = blockIdx.x*TPB + threadIdx.x;
  if (gid >= total) return;
  int rc = R*C;
  int l = gid / rc; int rem = gid - l*rc; int c = rem / R; int r = rem - c*R;
  dst[gid] = f2b(src[(size_t)l*rc + (size_t)r*C + c]);
}

__global__ __launch_bounds__(TPB) void tcvt_conv(const float* __restrict__ src,
    u16* __restrict__ dst, int total){
  int gid = blockIdx.x*TPB + threadIdx.x;
  if (gid >= total) return;
  int oc = gid / 576, k = gid - oc*576;
  int r9 = k >> 6, ic = k & 63;
  dst[gid] = f2b(src[oc*576 + ic*9 + r9]);
}

__global__ __launch_bounds__(TPB) void tcvt_cw(const float* __restrict__ src,
    float* __restrict__ dst){
  int gid = blockIdx.x*TPB + threadIdx.x;
  if (gid >= 393216) return;
  int i = gid / 384, rem = gid - i*384;
  int o = rem >> 3, e = rem & 7;
  dst[gid] = src[i*384 + e*48 + o];
}

// ---------------- LayerNorm (dim 64) -> bf16 H (once, before the loop)
__global__ __launch_bounds__(TPB) void ln_kernel(const float* __restrict__ x,
    const float* __restrict__ g, const float* __restrict__ bta, u16* __restrict__ out){
  int row = blockIdx.x*4 + (threadIdx.x>>6);
  int lane = threadIdx.x & 63;
  float v = x[(size_t)row*64 + lane];
  float s = v;
  #pragma unroll
  for (int off=32; off; off>>=1) s += __shfl_xor(s, off);
  float mean = s * (1.f/64.f);
  float d = v - mean;
  float q = d*d;
  #pragma unroll
  for (int off=32; off; off>>=1) q += __shfl_xor(q, off);
  float r = rsqrtf(q*(1.f/64.f) + 1e-5f);
  out[(size_t)row*64 + lane] = f2b(d*r*g[lane] + bta[lane]);
}

// ---------------- fused QKV-proj + attention (row form, low VGPR):
// one block per (head, sample). Kl stride 72 (2-way-free b128 reads);
// no max-subtract; 1/sum deferred to epilogue; PV in 3x64-key passes;
// coalesced O store via Pw transpose.
__global__ __launch_bounds__(TPB) void attn_fused(const u16* __restrict__ Hg,
    const u16* __restrict__ W, u16* __restrict__ Og){
  __shared__ __align__(16) u16 Kl[192][72];   // K [key][d], 144B rows
  __shared__ __align__(16) u16 VT[64][200];   // V^T [d][key], 400B rows
  __shared__ __align__(16) u16 Pw[4][16][72]; // wave-private transpose panel
  int h = blockIdx.x, s = blockIdx.y;
  int tid = threadIdx.x, wave = tid>>6, lane = tid&63;
  int q = lane>>4, li = lane&15;
  const u16* Hb = Hg + (size_t)s*180*64;
  const u16* Wq = W + (size_t)(h*64)*64;
  const u16* Wk = W + (size_t)(768 + h*64)*64;
  const u16* Wv = W + (size_t)(1536 + h*64)*64;
  // phase 1: K and V^T into LDS (rows >=180 are clamped clones, masked later)
  for (int p = wave; p < 12; p += 4){
    int m0 = p*16;
    int ar = m0 + li; if (ar > 179) ar = 179;
    const u16* hrow = Hb + (size_t)ar*64 + q*8;
    bf16x8 a0 = *(const bf16x8*)hrow;
    bf16x8 a1 = *(const bf16x8*)(hrow+32);
    #pragma unroll
    for (int nt=0; nt<4; nt++){
      const u16* kr = Wk + (size_t)(nt*16+li)*64 + q*8;
      bf16x8 b0 = *(const bf16x8*)kr;
      bf16x8 b1 = *(const bf16x8*)(kr+32);
      f32x4 ck = {0.f,0.f,0.f,0.f};
      ck = mfma16(a0,b0,ck); ck = mfma16(a1,b1,ck);
      #pragma unroll
      for (int r=0;r<4;r++) Kl[m0+q*4+r][nt*16+li] = f2b(ck[r]);
      const u16* vr = Wv + (size_t)(nt*16+li)*64 + q*8;
      bf16x8 d0 = *(const bf16x8*)vr;
      bf16x8 d1 = *(const bf16x8*)(vr+32);
      f32x4 cv = {0.f,0.f,0.f,0.f};
      cv = mfma16(a0,d0,cv); cv = mfma16(a1,d1,cv);
      #pragma unroll
      for (int r=0;r<4;r++) VT[nt*16+li][m0+q*4+r] = f2b(cv[r]);
    }
  }
  __syncthreads();
  // phase 2
  for (int p = wave; p < 12; p += 4){
    int m0 = p*16;
    int ar = m0 + li; if (ar > 179) ar = 179;
    const u16* hrow = Hb + (size_t)ar*64 + q*8;
    bf16x8 a0 = *(const bf16x8*)hrow;
    bf16x8 a1 = *(const bf16x8*)(hrow+32);
    // Q tile (pre-scaled) -> A-layout via Pw
    #pragma unroll
    for (int nt=0; nt<4; nt++){
      const u16* qr = Wq + (size_t)(nt*16+li)*64 + q*8;
      bf16x8 b0 = *(const bf16x8*)qr;
      bf16x8 b1 = *(const bf16x8*)(qr+32);
      f32x4 c = {0.f,0.f,0.f,0.f};
      c = mfma16(a0,b0,c); c = mfma16(a1,b1,c);
      #pragma unroll
      for (int r=0;r<4;r++) Pw[wave][q*4+r][nt*16+li] = f2b(c[r]*0.125f);
    }
    bf16x8 qf0 = *(const bf16x8*)&Pw[wave][li][q*8];
    bf16x8 qf1 = *(const bf16x8*)&Pw[wave][li][32+q*8];
    f32x4 S[12];
    #pragma unroll
    for (int t=0;t<12;t++){
      bf16x8 b0 = *(const bf16x8*)&Kl[t*16+li][q*8];
      bf16x8 b1 = *(const bf16x8*)&Kl[t*16+li][32+q*8];
      f32x4 c = {0.f,0.f,0.f,0.f};
      c = mfma16(qf0,b0,c); c = mfma16(qf1,b1,c);
      S[t] = c;
    }
    if (li >= 4){ S[11][0]=-1e30f; S[11][1]=-1e30f; S[11][2]=-1e30f; S[11][3]=-1e30f; }
    // row sums (no max: |scores| << 1; exp(-1e30) underflows to 0)
    float inv[4];
    #pragma unroll
    for (int r=0;r<4;r++){
      float sum = 0.f;
      #pragma unroll
      for (int t=0;t<12;t++) sum += __expf(S[t][r]);
      #pragma unroll
      for (int off=8; off; off>>=1) sum += __shfl_xor(sum, off);
      inv[r] = 1.f/sum;
    }
    // PV: 3 passes of 64 keys; P written raw (unnormalized), inv applied at end
    f32x4 acc[4];
    #pragma unroll
    for (int nd=0;nd<4;nd++) acc[nd] = (f32x4){0.f,0.f,0.f,0.f};
    #pragma unroll
    for (int g=0; g<3; g++){
      #pragma unroll
      for (int t=0;t<4;t++){
        #pragma unroll
        for (int r=0;r<4;r++)
          Pw[wave][q*4+r][t*16+li] = f2b(__expf(S[g*4+t][r]));
      }
      bf16x8 p0 = *(const bf16x8*)&Pw[wave][li][q*8];
      bf16x8 p1 = *(const bf16x8*)&Pw[wave][li][32+q*8];
      #pragma unroll
      for (int nd=0; nd<4; nd++){
        bf16x8 v0 = *(const bf16x8*)&VT[nd*16+li][g*64 + q*8];
        bf16x8 v1 = *(const bf16x8*)&VT[nd*16+li][g*64 + 32 + q*8];
        acc[nd] = mfma16(p0, v0, acc[nd]);
        acc[nd] = mfma16(p1, v1, acc[nd]);
      }
    }
    // epilogue: normalize, transpose via Pw, coalesced b128 stores
    #pragma unroll
    for (int nd=0; nd<4; nd++){
      #pragma unroll
      for (int r=0;r<4;r++)
        Pw[wave][q*4+r][nd*16+li] = f2b(acc[nd][r]*inv[r]);
    }
    int g8 = lane>>3, u8 = lane&7;
    #pragma unroll
    for (int it2=0; it2<2; it2++){
      int rr = it2*8 + g8;
      int row = m0 + rr;
      bf16x8 ov = *(const bf16x8*)&Pw[wave][rr][u8*8];
      if (row < 180)
        *(bf16x8*)(Og + (size_t)(s*180+row)*768 + h*64 + u8*8) = ov;
    }
  }
}

// ---------------- out-proj + residual + fused LN2 -> Hg
__global__ __launch_bounds__(TPB) void gemm_outp(const u16* __restrict__ Og,
    const u16* __restrict__ WOT, const float* __restrict__ outb,
    const float* __restrict__ lng, const float* __restrict__ lnb,
    float* __restrict__ t, u16* __restrict__ HgOut){
  int wave = threadIdx.x>>6, lane = threadIdx.x&63, q = lane>>4, li = lane&15;
  int m0 = blockIdx.x*64 + wave*16;
  f32x4 acc[4];
  #pragma unroll
  for (int nd=0;nd<4;nd++) acc[nd] = (f32x4){0.f,0.f,0.f,0.f};
  for (int kb=0; kb<24; kb++){
    bf16x8 a = *(const bf16x8*)(Og + (size_t)(m0+li)*768 + kb*32 + q*8);
    #pragma unroll
    for (int nd=0;nd<4;nd++){
      bf16x8 b = *(const bf16x8*)(WOT + (size_t)(nd*16+li)*768 + kb*32 + q*8);
      acc[nd] = mfma16(a, b, acc[nd]);
    }
  }
  float tv[4][4]; float gv[4], bvn[4];
  #pragma unroll
  for (int nd=0;nd<4;nd++){
    int col = nd*16 + li;
    float bv = outb[col];
    gv[nd] = lng[col]; bvn[nd] = lnb[col];
    #pragma unroll
    for (int r=0;r<4;r++){
      size_t off = (size_t)(m0 + q*4 + r)*64 + col;
      float v = t[off] + acc[nd][r] + bv;
      t[off] = v;
      tv[nd][r] = v;
    }
  }
  #pragma unroll
  for (int r=0;r<4;r++){
    float s = tv[0][r]+tv[1][r]+tv[2][r]+tv[3][r];
    #pragma unroll
    for (int off=8; off; off>>=1) s += __shfl_xor(s, off);
    float mean = s*(1.f/64.f);
    float qs = 0.f;
    #pragma unroll
    for (int nd=0;nd<4;nd++){ float d = tv[nd][r]-mean; qs += d*d; }
    #pragma unroll
    for (int off=8; off; off>>=1) qs += __shfl_xor(qs, off);
    float rinv = rsqrtf(qs*(1.f/64.f) + 1e-5f);
    size_t rowoff = (size_t)(m0 + q*4 + r)*64;
    #pragma unroll
    for (int nd=0;nd<4;nd++){
      int col = nd*16 + li;
      HgOut[rowoff + col] = f2b((tv[nd][r]-mean)*rinv*gv[nd] + bvn[nd]);
    }
  }
}

// ---------------- fused ffn: gelu(Hg@W1^T+b1) -> LDS panel -> t+=@W2^T+b2 -> LN(next) -> Hg
__global__ __launch_bounds__(TPB) void gemm_ffn(const u16* __restrict__ Hg,
    const u16* __restrict__ W1, const float* __restrict__ b1,
    const u16* __restrict__ W2, const float* __restrict__ b2,
    const float* __restrict__ lng, const float* __restrict__ lnb,
    float* __restrict__ t, u16* __restrict__ HgOut){
  __shared__ __align__(16) u16 panel[4][16][264];
  int wave = threadIdx.x>>6, lane = threadIdx.x&63, q = lane>>4, li = lane&15;
  int m0 = blockIdx.x*64 + wave*16;
  const u16* arow = Hg + (size_t)(m0+li)*64 + q*8;
  bf16x8 a0 = *(const bf16x8*)arow;
  bf16x8 a1 = *(const bf16x8*)(arow + 32);
  for (int nt=0; nt<16; nt++){
    const u16* brow = W1 + (size_t)(nt*16+li)*64 + q*8;
    bf16x8 b0 = *(const bf16x8*)brow;
    bf16x8 b1v = *(const bf16x8*)(brow + 32);
    f32x4 c = {0.f,0.f,0.f,0.f};
    c = mfma16(a0, b0, c);
    c = mfma16(a1, b1v, c);
    int col = nt*16 + li;
    float bv = b1[col];
    #pragma unroll
    for (int r=0;r<4;r++){
      float v = c[r] + bv;
      v = v*0.5f*(1.f + erff(v*0.70710678118f));
      panel[wave][q*4+r][col] = f2b(v);
    }
  }
  bf16x8 ap[8];
  #pragma unroll
  for (int kb=0;kb<8;kb++) ap[kb] = *(const bf16x8*)&panel[wave][li][kb*32 + q*8];
  f32x4 acc[4];
  #pragma unroll
  for (int nd=0;nd<4;nd++) acc[nd] = (f32x4){0.f,0.f,0.f,0.f};
  #pragma unroll
  for (int kb=0; kb<8; kb++){
    #pragma unroll
    for (int nd=0;nd<4;nd++){
      bf16x8 b = *(const bf16x8*)(W2 + (size_t)(nd*16+li)*256 + kb*32 + q*8);
      acc[nd] = mfma16(ap[kb], b, acc[nd]);
    }
  }
  float tv[4][4]; float gv[4], bvn[4];
  #pragma unroll
  for (int nd=0;nd<4;nd++){
    int col = nd*16 + li;
    float bv = b2[col];
    gv[nd] = lng[col]; bvn[nd] = lnb[col];
    #pragma unroll
    for (int r=0;r<4;r++){
      size_t off = (size_t)(m0 + q*4 + r)*64 + col;
      float v = t[off] + acc[nd][r] + bv;
      t[off] = v;
      tv[nd][r] = v;
    }
  }
  #pragma unroll
  for (int r=0;r<4;r++){
    float s = tv[0][r]+tv[1][r]+tv[2][r]+tv[3][r];
    #pragma unroll
    for (int off=8; off; off>>=1) s += __shfl_xor(s, off);
    float mean = s*(1.f/64.f);
    float qs = 0.f;
    #pragma unroll
    for (int nd=0;nd<4;nd++){ float d = tv[nd][r]-mean; qs += d*d; }
    #pragma unroll
    for (int off=8; off; off>>=1) qs += __shfl_xor(qs, off);
    float rinv = rsqrtf(qs*(1.f/64.f) + 1e-5f);
    size_t rowoff = (size_t)(m0 + q*4 + r)*64;
    #pragma unroll
    for (int nd=0;nd<4;nd++){
      int col = nd*16 + li;
      HgOut[rowoff + col] = f2b((tv[nd][r]-mean)*rinv*gv[nd] + bvn[nd]);
    }
  }
}

// ---------------- PrimaryCaps via MFMA + fused squash: one block per sample
__global__ __launch_bounds__(TPB) void pcaps_mfma(const float* __restrict__ t,
    const u16* __restrict__ wpc, const float* __restrict__ bias, float* __restrict__ caps){
  int b = blockIdx.x;
  int wave = threadIdx.x>>6, lane = threadIdx.x&63, q = lane>>4, li = lane&15;
  int mt = wave & 1, nh = wave >> 1;
  const float* tb = t + (size_t)b*180*64;
  int pos_a = mt*16 + li;
  int oy_a = pos_a >> 3, ox_a = pos_a & 7;
  f32x4 acc[8];
  #pragma unroll
  for (int nt=0;nt<8;nt++) acc[nt] = (f32x4){0.f,0.f,0.f,0.f};
  for (int ks=0; ks<18; ks++){
    int k0 = ks*32 + q*8;
    int r9 = k0 >> 6, ic = k0 & 63;
    int dy = r9/3, dx = r9 - 3*dy;
    const float* src = tb + ((2*oy_a+dy)*18 + (2*ox_a+dx))*64 + ic;
    float4 f0 = *(const float4*)src;
    float4 f1 = *(const float4*)(src+4);
    bf16x8 a;
    a[0]=(short)f2b(f0.x); a[1]=(short)f2b(f0.y); a[2]=(short)f2b(f0.z); a[3]=(short)f2b(f0.w);
    a[4]=(short)f2b(f1.x); a[5]=(short)f2b(f1.y); a[6]=(short)f2b(f1.z); a[7]=(short)f2b(f1.w);
    #pragma unroll
    for (int nt=0;nt<8;nt++){
      bf16x8 bb8 = *(const bf16x8*)(wpc + (size_t)(nh*128 + nt*16 + li)*576 + k0);
      acc[nt] = mfma16(a, bb8, acc[nt]);
    }
  }
  #pragma unroll
  for (int nt=0;nt<8;nt++){
    int oc = nh*128 + nt*16 + li;
    float bv = bias[oc];
    #pragma unroll
    for (int r=0;r<4;r++){
      int prow = mt*16 + q*4 + r;
      float val = acc[nt][r] + bv;
      float l2 = val*val;
      l2 += __shfl_xor(l2, 1);
      l2 += __shfl_xor(l2, 2);
      l2 += __shfl_xor(l2, 4);
      float sc = (l2 > 0.f) ? l2/((1.f+l2)*sqrtf(l2)) : 0.f;
      caps[((size_t)b*1024 + (oc>>3)*32 + prow)*8 + (oc&7)] = val*sc;
    }
  }
}

// ---------------- u[b,i,o] = caps[b,i,:] . cwT[i,o,:]
__global__ __launch_bounds__(TPB) void u_kernel(const float* __restrict__ caps,
    const float* __restrict__ cwT, float* __restrict__ u){
  int gid = blockIdx.x*TPB + threadIdx.x;
  int o = gid % 48; int i = (gid/48) & 1023; int b = gid/(48*1024);
  const float* cp = caps + ((size_t)b*1024 + i)*8;
  const float* wp = cwT + ((size_t)i*48 + o)*8;
  float4 c0 = *(const float4*)cp, c1 = *(const float4*)(cp+4);
  float4 w0 = *(const float4*)wp, w1 = *(const float4*)(wp+4);
  u[gid] = c0.x*w0.x + c0.y*w0.y + c0.z*w0.z + c0.w*w0.w
         + c1.x*w1.x + c1.y*w1.y + c1.z*w1.z + c1.w*w1.w;
}

__global__ __launch_bounds__(TPB) void routing_kernel(const float* __restrict__ u,
    const float* __restrict__ b_route, float* __restrict__ out){
  __shared__ float bb[3072];
  __shared__ float vsh[48];
  __shared__ float red[4][48];
  __shared__ float ssh[48];
  int b = blockIdx.x, tid = threadIdx.x;
  const float* ub = u + (size_t)b*49152;
  for (int idx=tid; idx<3072; idx+=TPB) bb[idx] = b_route[idx];
  __syncthreads();
  for (int it=0; it<4; it++){
    if (it > 0){
      for (int idx=tid; idx<3072; idx+=TPB){
        int i = idx/3, j = idx - i*3;
        const float* up = ub + i*48 + j*16;
        float s = 0.f;
        #pragma unroll
        for (int e=0;e<16;e++) s += up[e]*vsh[j*16+e];
        bb[idx] += s;
      }
      __syncthreads();
    }
    float acc[48];
    #pragma unroll
    for (int q2=0;q2<48;q2++) acc[q2] = 0.f;
    for (int i=tid; i<1024; i+=TPB){
      float b0=bb[i*3], b1=bb[i*3+1], b2v=bb[i*3+2];
      float m = fmaxf(b0, fmaxf(b1, b2v));
      float e0=__expf(b0-m), e1=__expf(b1-m), e2=__expf(b2v-m);
      float inv = 1.f/(e0+e1+e2);
      float c0=e0*inv, c1=e1*inv, c2=e2*inv;
      const float* up = ub + i*48;
      #pragma unroll
      for (int e=0;e<16;e++){
        acc[e]    += c0*up[e];
        acc[16+e] += c1*up[16+e];
        acc[32+e] += c2*up[32+e];
      }
    }
    #pragma unroll
    for (int q2=0;q2<48;q2++){
      float v = acc[q2];
      #pragma unroll
      for (int off=32; off; off>>=1) v += __shfl_xor(v, off);
      if ((tid&63)==0) red[tid>>6][q2] = v;
    }
    __syncthreads();
    if (tid < 48) ssh[tid] = red[0][tid]+red[1][tid]+red[2][tid]+red[3][tid];
    __syncthreads();
    if (tid < 48){
      int j = tid >> 4;
      float l2 = 0.f;
      #pragma unroll
      for (int e=0;e<16;e++) l2 += ssh[j*16+e]*ssh[j*16+e];
      float sc = (l2 > 0.f) ? l2/((1.f+l2)*sqrtf(l2)) : 0.f;
      vsh[tid] = ssh[tid]*sc;
    }
    __syncthreads();
  }
  if (tid < 3){
    float l2 = 0.f;
    #pragma unroll
    for (int e=0;e<16;e++) l2 += vsh[tid*16+e]*vsh[tid*16+e];
    out[b*3+tid] = sqrtf(l2);
  }
}

extern "C" void kernel_launch(void* const* d_in, const int* in_sizes, int n_in,
                              void* d_out, int out_size, void* d_ws, size_t ws_size,
                              hipStream_t stream){
  const float* x       = (const float*)d_in[0];
  const float* conv1_w = (const float*)d_in[1];
  const float* conv2_w = (const float*)d_in[2];
  const float* pos_emb = (const float*)d_in[3];
  const float* ln1_g   = (const float*)d_in[4];
  const float* ln1_b   = (const float*)d_in[5];
  const float* qkv_w   = (const float*)d_in[6];
  const float* out_w   = (const float*)d_in[7];
  const float* out_b   = (const float*)d_in[8];
  const float* ln2_g   = (const float*)d_in[9];
  const float* ln2_b   = (const float*)d_in[10];
  const float* ff1_w   = (const float*)d_in[11];
  const float* ff1_b   = (const float*)d_in[12];
  const float* ff2_w   = (const float*)d_in[13];
  const float* ff2_b   = (const float*)d_in[14];
  const float* pc_w    = (const float*)d_in[15];
  const float* pc_b    = (const float*)d_in[16];
  const float* caps_w  = (const float*)d_in[17];
  const float* b_route = (const float*)d_in[18];
  float* out = (float*)d_out;

  // ---- workspace: peak 95,920,128 B (< 97.3 MB proven safe) ----
  char* ws = (char*)d_ws;
  float* t_buf = (float*)(ws);                  // [46080,64] f32
  u16*  Hg    = (u16*)(ws + 11796480);          // [46080,64] bf16
  u16*  WQKVT = (u16*)(ws + 17694720);          // [12][2304][64]
  u16*  WOT   = (u16*)(ws + 21233664);          // [12][64][768]
  u16*  WF1T  = (u16*)(ws + 22413312);          // [12][256][64]
  u16*  WF2T  = (u16*)(ws + 22806528);          // [12][64][256]
  u16*  wpc   = (u16*)(ws + 23199744);          // [256][576] bf16
  float* cwT  = (float*)(ws + 23494656);        // [1024][48][8]
  u16*  wc2   = (u16*)(ws + 25067520);          // [64][576] bf16
  char* win   = ws + 25141248;                  // 70,778,880 B window
  u16*  Og    = (u16*)win;                      // [46080][768] bf16
  u16*  p1out = (u16*)win;                      // [256][720][64] bf16
  u16*  c1out = (u16*)(win + 23592960);         // [64][2880][64] bf16 chunk
  float* c2out = (float*)(win + 23592960);      // [256][720][64] f32
  float* caps  = (float*)(win);                 // tail
  float* u_buf = (float*)(win + 8388608);       // tail

  // ---- weight prep ----
  tcvt_kernel<<<6912, TPB, 0, stream>>>(qkv_w, WQKVT, 64, 2304, 12*64*2304);
  tcvt_kernel<<<2304, TPB, 0, stream>>>(out_w, WOT, 768, 64, 12*768*64);
  tcvt_kernel<<<768, TPB, 0, stream>>>(ff1_w, WF1T, 64, 256, 12*64*256);
  tcvt_kernel<<<768, TPB, 0, stream>>>(ff2_w, WF2T, 256, 64, 12*256*64);
  tcvt_conv<<<576, TPB, 0, stream>>>(pc_w, wpc, 147456);
  tcvt_conv<<<144, TPB, 0, stream>>>(conv2_w, wc2, 36864);
  tcvt_cw<<<1536, TPB, 0, stream>>>(caps_w, cwT);

  // ---- conv-embed ----
  for (int c = 0; c < 4; c++){
    conv1_kernel<<<1440, TPB, 0, stream>>>(x + (size_t)c*64*3*2880, conv1_w, c1out);
    maxpool1_kernel<<<2880, TPB, 0, stream>>>(c1out, p1out + (size_t)c*64*720*64);
  }
  conv2_mfma<<<dim3(12,256), TPB, 0, stream>>>(p1out, wc2, c2out);
  pool2pos_kernel<<<2880, TPB, 0, stream>>>(c2out, pos_emb, t_buf);

  // ---- transformer ----
  ln_kernel<<<11520, TPB, 0, stream>>>(t_buf, ln1_g, ln1_b, Hg);
  for (int itr=0; itr<24; itr++){
    int l = itr % 12;
    int ln = (itr+1) % 12;
    attn_fused<<<dim3(12,256), TPB, 0, stream>>>(Hg, WQKVT + (size_t)l*2304*64, Og);
    gemm_outp<<<720, TPB, 0, stream>>>(Og, WOT + (size_t)l*64*768, out_b + l*64,
                                       ln2_g + l*64, ln2_b + l*64, t_buf, Hg);
    gemm_ffn<<<720, TPB, 0, stream>>>(Hg, WF1T + (size_t)l*256*64, ff1_b + l*256,
                                      WF2T + (size_t)l*64*256, ff2_b + l*64,
                                      ln1_g + ln*64, ln1_b + ln*64, t_buf, Hg);
  }

  // ---- capsule head ----
  pcaps_mfma<<<256, TPB, 0, stream>>>(t_buf, wpc, pc_b, caps);
  u_kernel<<<49152, TPB, 0, stream>>>(caps, cwT, u_buf);
  routing_kernel<<<256, TPB, 0, stream>>>(u_buf, b_route, out);
}